// Round 2
// baseline (564.683 us; speedup 1.0000x reference)
//
#include <hip/hip_runtime.h>

// Shapes fixed by the reference: N=M=512, B=1, C=256, H=8, Dh=32, fp32.

// ---------------- Kernel 1: transpose Wq/Wk/Wv (256x256 each) ----------------
__global__ __launch_bounds__(256) void k_transpose(const float* __restrict__ Wq,
                                                   const float* __restrict__ Wk,
                                                   const float* __restrict__ Wv,
                                                   float* __restrict__ wt) {
  const float* W = (blockIdx.y == 0) ? Wq : (blockIdx.y == 1) ? Wk : Wv;
  float* O = wt + (size_t)blockIdx.y * 65536;
  __shared__ float t[64][65];
  const int tile = blockIdx.x;
  const int tr = (tile >> 2) * 64, tc = (tile & 3) * 64;
  const int c = threadIdx.x & 63, r0 = threadIdx.x >> 6;
#pragma unroll
  for (int i = 0; i < 16; ++i) {
    int r = r0 + i * 4;
    t[r][c] = W[(tr + r) * 256 + tc + c];
  }
  __syncthreads();
#pragma unroll
  for (int i = 0; i < 16; ++i) {
    int r = r0 + i * 4;
    O[(tc + r) * 256 + tr + c] = t[c][r];  // O[a][b] = W[b][a]
  }
}

// ---------------- Kernel 2: projections q,k,v = x @ W^T + b ----------------
__global__ __launch_bounds__(256) void k_proj(const float* __restrict__ q_in,
                                              const float* __restrict__ k_in,
                                              const float* __restrict__ v_in,
                                              const float* __restrict__ bq,
                                              const float* __restrict__ bk,
                                              const float* __restrict__ bv,
                                              const float* __restrict__ wt,
                                              float* __restrict__ outb) {
  const int mat = blockIdx.y;
  const float* x = mat == 0 ? q_in : mat == 1 ? k_in : v_in;
  const float* b = mat == 0 ? bq : mat == 1 ? bk : bv;
  const float* WT = wt + (size_t)mat * 65536;
  float* out = outb + (size_t)mat * 131072;

  __shared__ float xl[8][256];
  const int tid = threadIdx.x;
  const int n0 = blockIdx.x * 8;
  for (int idx = tid; idx < 2048; idx += 256)
    xl[idx >> 8][idx & 255] = x[(n0 + (idx >> 8)) * 256 + (idx & 255)];
  __syncthreads();

  float acc[8] = {0.f, 0.f, 0.f, 0.f, 0.f, 0.f, 0.f, 0.f};
  for (int j = 0; j < 256; j += 4) {
    const float w0 = WT[(j + 0) * 256 + tid];
    const float w1 = WT[(j + 1) * 256 + tid];
    const float w2 = WT[(j + 2) * 256 + tid];
    const float w3 = WT[(j + 3) * 256 + tid];
#pragma unroll
    for (int r = 0; r < 8; ++r) {
      const float4 xv = *(const float4*)&xl[r][j];
      acc[r] += xv.x * w0 + xv.y * w1 + xv.z * w2 + xv.w * w3;
    }
  }
  const float bb = b[tid];
#pragma unroll
  for (int r = 0; r < 8; ++r) out[(n0 + r) * 256 + tid] = acc[r] + bb;
}

// ---------------- Kernel 3: t[n][h][j] = sum_{i in h} q[n,i]*Wg[i,j]; qb[n][h] ----------------
// grid (8 n-tiles of 64, 8 heads), 256 threads.
__global__ __launch_bounds__(256) void k_tfold(const float* __restrict__ qkv,
                                               const float* __restrict__ Wg,
                                               const float* __restrict__ bg,
                                               float* __restrict__ t_ws,
                                               float* __restrict__ qb_ws) {
  const int h = blockIdx.y;
  const int n0 = blockIdx.x * 64;
  const int tid = threadIdx.x;
  __shared__ float wg_s[32][256];
  __shared__ float qs[64][32];
  __shared__ float bgs[32];

  // stage Wg head-slab (32 rows x 256 cols), coalesced
  for (int idx = tid; idx < 8192; idx += 256)
    wg_s[idx >> 8][idx & 255] = Wg[(size_t)(h * 32 + (idx >> 8)) * 256 + (idx & 255)];
  // stage q slab (64 n x 32 ch)
  for (int idx = tid; idx < 2048; idx += 256)
    qs[idx >> 5][idx & 31] = qkv[(size_t)(n0 + (idx >> 5)) * 256 + h * 32 + (idx & 31)];
  if (tid < 32) bgs[tid] = bg[h * 32 + tid];
  __syncthreads();

  float wr[32];
#pragma unroll
  for (int i = 0; i < 32; ++i) wr[i] = wg_s[i][tid];
  for (int nn = 0; nn < 64; ++nn) {
    float a = 0.f;
#pragma unroll
    for (int i = 0; i < 32; ++i) a = fmaf(qs[nn][i], wr[i], a);
    t_ws[(size_t)(n0 + nn) * 2048 + h * 256 + tid] = a;
  }
  if (tid < 64) {
    float a = 0.f;
#pragma unroll
    for (int i = 0; i < 32; ++i) a = fmaf(qs[tid][i], bgs[i], a);
    qb_ws[(n0 + tid) * 8 + h] = a;
  }
}

// ---------------- Kernel 4: raw scores for one (n, m-chunk of 128) ----------------
// grid (512, 4), 256 threads = 4 waves. Writes raw scaled scores to attn region.
__global__ __launch_bounds__(256, 4) void k_scores(const float* __restrict__ Eg,
                                                   const float* __restrict__ qkv,
                                                   const float* __restrict__ t_ws,
                                                   const float* __restrict__ qb_ws,
                                                   float* __restrict__ attn_raw) {
  const int n = blockIdx.x, mb = blockIdx.y;
  const int tid = threadIdx.x;
  const int lane = tid & 63, w = tid >> 6;
  const int g = lane >> 3, s = lane & 7;
  const float* k_g = qkv + 131072;

  __shared__ float ql[256];
  __shared__ float tl[2048];
  __shared__ float qbl[8];
  __shared__ float p_lds[1024];

  ql[tid] = qkv[n * 256 + tid];
  {
    const float4* src = (const float4*)(t_ws + (size_t)n * 2048);
    float4* dst = (float4*)tl;
    dst[tid] = src[tid];
    dst[tid + 256] = src[tid + 256];
  }
  if (tid < 8) qbl[tid] = qb_ws[n * 8 + tid];
  __syncthreads();

  const float scale = 0.17677669529663687f;  // 1/sqrt(32)

#pragma unroll
  for (int it = 0; it < 2; ++it) {
    const int mo = w * 32 + it * 16 + g;   // [0,128) within chunk
    const int m0 = mb * 128 + mo;          // global m
    const float* E0 = Eg + ((size_t)n * 512 + m0) * 256 + s * 4;
    const float* K0 = k_g + (size_t)m0 * 256 + s * 4;
    float acc0[8] = {0.f, 0.f, 0.f, 0.f, 0.f, 0.f, 0.f, 0.f};
    float acc1[8] = {0.f, 0.f, 0.f, 0.f, 0.f, 0.f, 0.f, 0.f};
#pragma unroll
    for (int j = 0; j < 8; ++j) {
      const int c0 = j * 32;
      const float4 ea = *(const float4*)(E0 + c0);
      const float4 eb = *(const float4*)(E0 + 2048 + c0);
      const float4 ka = *(const float4*)(K0 + c0);
      const float4 kb = *(const float4*)(K0 + 2048 + c0);
      const float4 q4 = *(const float4*)&ql[c0 + s * 4];
      // scores_e: chunk j covers exactly head j's 32 channels
      acc0[j] += ka.x * q4.x + ka.y * q4.y + ka.z * q4.z + ka.w * q4.w;
      acc1[j] += kb.x * q4.x + kb.y * q4.y + kb.z * q4.z + kb.w * q4.w;
#pragma unroll
      for (int h = 0; h < 8; ++h) {
        const float4 t4 = *(const float4*)&tl[h * 256 + c0 + s * 4];
        acc0[h] += ea.x * t4.x + ea.y * t4.y + ea.z * t4.z + ea.w * t4.w;
        acc1[h] += eb.x * t4.x + eb.y * t4.y + eb.z * t4.z + eb.w * t4.w;
      }
    }
#pragma unroll
    for (int h = 0; h < 8; ++h) {
      float a0 = acc0[h], a1 = acc1[h];
      a0 += __shfl_xor(a0, 1); a0 += __shfl_xor(a0, 2); a0 += __shfl_xor(a0, 4);
      a1 += __shfl_xor(a1, 1); a1 += __shfl_xor(a1, 2); a1 += __shfl_xor(a1, 4);
      const float s0 = (a0 + qbl[h]) * scale;
      const float s1 = (a1 + qbl[h]) * scale;
      if (s == h) {
        p_lds[h * 128 + mo] = s0;
        p_lds[h * 128 + mo + 8] = s1;
      }
    }
  }
  __syncthreads();
  for (int idx = tid; idx < 1024; idx += 256)
    attn_raw[(size_t)(idx >> 7) * 262144 + n * 512 + mb * 128 + (idx & 127)] = p_lds[idx];
}

// ---------------- Kernel 5: softmax + attn normalize (in-place) + attn@v ----------------
// grid 512 (one per n), 512 threads = 8 waves (wave w = head w for softmax).
__global__ __launch_bounds__(512) void k_finish(const float* __restrict__ qkv,
                                                float* __restrict__ out) {
  const float* v_g = qkv + 262144;
  const int n = blockIdx.x, tid = threadIdx.x;
  const int lane = tid & 63, w = tid >> 6;
  float* attn = out + 131072;

  __shared__ float sc[4096];     // [8 heads][512 m]
  __shared__ float invd[8];
  __shared__ float pv[2][256];

  {
    float4* d = (float4*)sc;
    int i0 = tid;
    d[i0] = *(const float4*)(attn + (size_t)(i0 >> 7) * 262144 + n * 512 + (i0 & 127) * 4);
    int i1 = tid + 512;
    d[i1] = *(const float4*)(attn + (size_t)(i1 >> 7) * 262144 + n * 512 + (i1 & 127) * 4);
  }
  __syncthreads();

  // softmax over m for head w
  {
    float vals[8];
#pragma unroll
    for (int i = 0; i < 8; ++i) vals[i] = sc[w * 512 + lane + i * 64];
    float mx = vals[0];
#pragma unroll
    for (int i = 1; i < 8; ++i) mx = fmaxf(mx, vals[i]);
#pragma unroll
    for (int off = 1; off < 64; off <<= 1) mx = fmaxf(mx, __shfl_xor(mx, off));
    float sum = 0.f;
#pragma unroll
    for (int i = 0; i < 8; ++i) {
      const float e = __expf(vals[i] - mx);
      sum += e;
      sc[w * 512 + lane + i * 64] = e;
    }
#pragma unroll
    for (int off = 1; off < 64; off <<= 1) sum += __shfl_xor(sum, off);
    if (lane == 0) invd[w] = 1.f / sum;
  }
  __syncthreads();

  // normalized attn write (in-place over raw scores)
#pragma unroll
  for (int r = 0; r < 8; ++r) {
    const int idx = tid + r * 512;
    const int h = idx >> 9, m = idx & 511;
    attn[(size_t)h * 262144 + n * 512 + m] = sc[idx] * invd[h];
  }

  // hidden[n,c] = (sum_m p[h][m] * v[m,c]) * invd[h]; split m across 2 thread-halves
  const int c = tid & 255, half = tid >> 8, h2 = c >> 5;
  const float* pr = sc + h2 * 512 + half * 256;
  const float* vp = v_g + (size_t)half * 65536 + c;
  float acc = 0.f;
#pragma unroll 4
  for (int m4 = 0; m4 < 64; ++m4) {
    const float4 p4 = *(const float4*)(pr + m4 * 4);
    const int mb = m4 * 4;
    acc = fmaf(p4.x, vp[(size_t)(mb + 0) * 256], acc);
    acc = fmaf(p4.y, vp[(size_t)(mb + 1) * 256], acc);
    acc = fmaf(p4.z, vp[(size_t)(mb + 2) * 256], acc);
    acc = fmaf(p4.w, vp[(size_t)(mb + 3) * 256], acc);
  }
  pv[half][c] = acc;
  __syncthreads();
  if (tid < 256) out[n * 256 + tid] = (pv[0][tid] + pv[1][tid]) * invd[tid >> 5];
}

extern "C" void kernel_launch(void* const* d_in, const int* in_sizes, int n_in,
                              void* d_out, int out_size, void* d_ws, size_t ws_size,
                              hipStream_t stream) {
  const float* query = (const float*)d_in[0];
  const float* key   = (const float*)d_in[1];
  const float* value = (const float*)d_in[2];
  const float* Eg    = (const float*)d_in[3];
  const float* Wq    = (const float*)d_in[4];
  const float* bq    = (const float*)d_in[5];
  const float* Wk    = (const float*)d_in[6];
  const float* bk    = (const float*)d_in[7];
  const float* Wv    = (const float*)d_in[8];
  const float* bv    = (const float*)d_in[9];
  const float* Wg    = (const float*)d_in[10];
  const float* bg    = (const float*)d_in[11];
  float* out = (float*)d_out;

  // ws layout (floats): wt[3*65536] | qkv[3*131072] | t_ws[512*2048] | qb_ws[4096]  ≈ 6.6 MB
  float* ws = (float*)d_ws;
  float* wt = ws;
  float* qkv = wt + 3 * 65536;
  float* t_ws = qkv + 3 * 131072;
  float* qb_ws = t_ws + 512 * 2048;

  k_transpose<<<dim3(16, 3), 256, 0, stream>>>(Wq, Wk, Wv, wt);
  k_proj<<<dim3(64, 3), 256, 0, stream>>>(query, key, value, bq, bk, bv, wt, qkv);
  k_tfold<<<dim3(8, 8), 256, 0, stream>>>(qkv, Wg, bg, t_ws, qb_ws);
  k_scores<<<dim3(512, 4), 256, 0, stream>>>(Eg, qkv, t_ws, qb_ws, out + 131072);
  k_finish<<<dim3(512), 512, 0, stream>>>(qkv, out);
}

// Round 3
// 142.191 us; speedup vs baseline: 3.9713x; 3.9713x over previous
//
#include <hip/hip_runtime.h>

// Shapes fixed by the reference: N=M=512, B=1, C=256, H=8, Dh=32, fp32.

// ---------------- Kernel 1: transpose Wq/Wk/Wv (256x256 each) ----------------
__global__ __launch_bounds__(256) void k_transpose(const float* __restrict__ Wq,
                                                   const float* __restrict__ Wk,
                                                   const float* __restrict__ Wv,
                                                   float* __restrict__ wt) {
  const float* W = (blockIdx.y == 0) ? Wq : (blockIdx.y == 1) ? Wk : Wv;
  float* O = wt + (size_t)blockIdx.y * 65536;
  __shared__ float t[64][65];
  const int tile = blockIdx.x;
  const int tr = (tile >> 2) * 64, tc = (tile & 3) * 64;
  const int c = threadIdx.x & 63, r0 = threadIdx.x >> 6;
#pragma unroll
  for (int i = 0; i < 16; ++i) {
    int r = r0 + i * 4;
    t[r][c] = W[(tr + r) * 256 + tc + c];
  }
  __syncthreads();
#pragma unroll
  for (int i = 0; i < 16; ++i) {
    int r = r0 + i * 4;
    O[(tc + r) * 256 + tr + c] = t[c][r];  // O[a][b] = W[b][a]
  }
}

// ---------------- Kernel 2: projections q,k,v = x @ W^T + b ----------------
__global__ __launch_bounds__(256) void k_proj(const float* __restrict__ q_in,
                                              const float* __restrict__ k_in,
                                              const float* __restrict__ v_in,
                                              const float* __restrict__ bq,
                                              const float* __restrict__ bk,
                                              const float* __restrict__ bv,
                                              const float* __restrict__ wt,
                                              float* __restrict__ outb) {
  const int mat = blockIdx.y;
  const float* x = mat == 0 ? q_in : mat == 1 ? k_in : v_in;
  const float* b = mat == 0 ? bq : mat == 1 ? bk : bv;
  const float* WT = wt + (size_t)mat * 65536;
  float* out = outb + (size_t)mat * 131072;

  __shared__ float xl[8][256];
  const int tid = threadIdx.x;
  const int n0 = blockIdx.x * 8;
  for (int idx = tid; idx < 2048; idx += 256)
    xl[idx >> 8][idx & 255] = x[(n0 + (idx >> 8)) * 256 + (idx & 255)];
  __syncthreads();

  float acc[8] = {0.f, 0.f, 0.f, 0.f, 0.f, 0.f, 0.f, 0.f};
  for (int j = 0; j < 256; j += 4) {
    const float w0 = WT[(j + 0) * 256 + tid];
    const float w1 = WT[(j + 1) * 256 + tid];
    const float w2 = WT[(j + 2) * 256 + tid];
    const float w3 = WT[(j + 3) * 256 + tid];
#pragma unroll
    for (int r = 0; r < 8; ++r) {
      const float4 xv = *(const float4*)&xl[r][j];
      acc[r] += xv.x * w0 + xv.y * w1 + xv.z * w2 + xv.w * w3;
    }
  }
  const float bb = b[tid];
#pragma unroll
  for (int r = 0; r < 8; ++r) out[(n0 + r) * 256 + tid] = acc[r] + bb;
}

// ---------------- Kernel 3: t[n][h][j] = sum_{i in h} q[n,i]*Wg[i,j]; qb[n][h] ----------------
// grid (8 n-tiles of 64, 8 heads), 256 threads.
__global__ __launch_bounds__(256) void k_tfold(const float* __restrict__ qkv,
                                               const float* __restrict__ Wg,
                                               const float* __restrict__ bg,
                                               float* __restrict__ t_ws,
                                               float* __restrict__ qb_ws) {
  const int h = blockIdx.y;
  const int n0 = blockIdx.x * 64;
  const int tid = threadIdx.x;
  __shared__ float wg_s[32][256];
  __shared__ float qs[64][32];
  __shared__ float bgs[32];

  // stage Wg head-slab (32 rows x 256 cols), coalesced
  for (int idx = tid; idx < 8192; idx += 256)
    wg_s[idx >> 8][idx & 255] = Wg[(size_t)(h * 32 + (idx >> 8)) * 256 + (idx & 255)];
  // stage q slab (64 n x 32 ch)
  for (int idx = tid; idx < 2048; idx += 256)
    qs[idx >> 5][idx & 31] = qkv[(size_t)(n0 + (idx >> 5)) * 256 + h * 32 + (idx & 31)];
  if (tid < 32) bgs[tid] = bg[h * 32 + tid];
  __syncthreads();

  float wr[32];
#pragma unroll
  for (int i = 0; i < 32; ++i) wr[i] = wg_s[i][tid];
  for (int nn = 0; nn < 64; ++nn) {
    float a = 0.f;
#pragma unroll
    for (int i = 0; i < 32; ++i) a = fmaf(qs[nn][i], wr[i], a);
    t_ws[(size_t)(n0 + nn) * 2048 + h * 256 + tid] = a;
  }
  if (tid < 64) {
    float a = 0.f;
#pragma unroll
    for (int i = 0; i < 32; ++i) a = fmaf(qs[tid][i], bgs[i], a);
    qb_ws[(n0 + tid) * 8 + h] = a;
  }
}

// ---------------- Kernel 4: raw scores for one (n, m-chunk of 128) ----------------
// grid (512, 4), 256 threads = 4 waves. Writes raw scaled scores to attn region.
// NOTE: no min-waves hint — forcing occupancy caused 64-VGPR spills (1 GB of
// scratch traffic, round 2). Unconstrained the loop fits ~160-220 VGPR, no spill.
__global__ __launch_bounds__(256) void k_scores(const float* __restrict__ Eg,
                                                const float* __restrict__ qkv,
                                                const float* __restrict__ t_ws,
                                                const float* __restrict__ qb_ws,
                                                float* __restrict__ attn_raw) {
  const int n = blockIdx.x, mb = blockIdx.y;
  const int tid = threadIdx.x;
  const int lane = tid & 63, w = tid >> 6;
  const int g = lane >> 3, s = lane & 7;
  const float* k_g = qkv + 131072;

  __shared__ float ql[256];
  __shared__ float tl[2048];
  __shared__ float qbl[8];
  __shared__ float p_lds[1024];

  ql[tid] = qkv[n * 256 + tid];
  {
    const float4* src = (const float4*)(t_ws + (size_t)n * 2048);
    float4* dst = (float4*)tl;
    dst[tid] = src[tid];
    dst[tid + 256] = src[tid + 256];
  }
  if (tid < 8) qbl[tid] = qb_ws[n * 8 + tid];
  __syncthreads();

  const float scale = 0.17677669529663687f;  // 1/sqrt(32)

#pragma unroll
  for (int it = 0; it < 2; ++it) {
    const int mo = w * 32 + it * 16 + g;   // [0,128) within chunk
    const int m0 = mb * 128 + mo;          // global m
    const float* E0 = Eg + ((size_t)n * 512 + m0) * 256 + s * 4;
    const float* K0 = k_g + (size_t)m0 * 256 + s * 4;
    float acc0[8] = {0.f, 0.f, 0.f, 0.f, 0.f, 0.f, 0.f, 0.f};
    float acc1[8] = {0.f, 0.f, 0.f, 0.f, 0.f, 0.f, 0.f, 0.f};
#pragma unroll
    for (int j = 0; j < 8; ++j) {
      const int c0 = j * 32;
      const float4 ea = *(const float4*)(E0 + c0);
      const float4 eb = *(const float4*)(E0 + 2048 + c0);
      const float4 ka = *(const float4*)(K0 + c0);
      const float4 kb = *(const float4*)(K0 + 2048 + c0);
      const float4 q4 = *(const float4*)&ql[c0 + s * 4];
      // scores_e: chunk j covers exactly head j's 32 channels
      acc0[j] += ka.x * q4.x + ka.y * q4.y + ka.z * q4.z + ka.w * q4.w;
      acc1[j] += kb.x * q4.x + kb.y * q4.y + kb.z * q4.z + kb.w * q4.w;
#pragma unroll
      for (int h = 0; h < 8; ++h) {
        const float4 t4 = *(const float4*)&tl[h * 256 + c0 + s * 4];
        acc0[h] += ea.x * t4.x + ea.y * t4.y + ea.z * t4.z + ea.w * t4.w;
        acc1[h] += eb.x * t4.x + eb.y * t4.y + eb.z * t4.z + eb.w * t4.w;
      }
    }
#pragma unroll
    for (int h = 0; h < 8; ++h) {
      float a0 = acc0[h], a1 = acc1[h];
      a0 += __shfl_xor(a0, 1); a0 += __shfl_xor(a0, 2); a0 += __shfl_xor(a0, 4);
      a1 += __shfl_xor(a1, 1); a1 += __shfl_xor(a1, 2); a1 += __shfl_xor(a1, 4);
      const float s0 = (a0 + qbl[h]) * scale;
      const float s1 = (a1 + qbl[h]) * scale;
      if (s == h) {
        p_lds[h * 128 + mo] = s0;
        p_lds[h * 128 + mo + 8] = s1;
      }
    }
  }
  __syncthreads();
  for (int idx = tid; idx < 1024; idx += 256)
    attn_raw[(size_t)(idx >> 7) * 262144 + n * 512 + mb * 128 + (idx & 127)] = p_lds[idx];
}

// ---------------- Kernel 5: softmax + attn normalize (in-place) + attn@v ----------------
// grid 512 (one per n), 512 threads = 8 waves (wave w = head w for softmax).
__global__ __launch_bounds__(512) void k_finish(const float* __restrict__ qkv,
                                                float* __restrict__ out) {
  const float* v_g = qkv + 262144;
  const int n = blockIdx.x, tid = threadIdx.x;
  const int lane = tid & 63, w = tid >> 6;
  float* attn = out + 131072;

  __shared__ float sc[4096];     // [8 heads][512 m]
  __shared__ float invd[8];
  __shared__ float pv[2][256];

  {
    float4* d = (float4*)sc;
    int i0 = tid;
    d[i0] = *(const float4*)(attn + (size_t)(i0 >> 7) * 262144 + n * 512 + (i0 & 127) * 4);
    int i1 = tid + 512;
    d[i1] = *(const float4*)(attn + (size_t)(i1 >> 7) * 262144 + n * 512 + (i1 & 127) * 4);
  }
  __syncthreads();

  // softmax over m for head w
  {
    float vals[8];
#pragma unroll
    for (int i = 0; i < 8; ++i) vals[i] = sc[w * 512 + lane + i * 64];
    float mx = vals[0];
#pragma unroll
    for (int i = 1; i < 8; ++i) mx = fmaxf(mx, vals[i]);
#pragma unroll
    for (int off = 1; off < 64; off <<= 1) mx = fmaxf(mx, __shfl_xor(mx, off));
    float sum = 0.f;
#pragma unroll
    for (int i = 0; i < 8; ++i) {
      const float e = __expf(vals[i] - mx);
      sum += e;
      sc[w * 512 + lane + i * 64] = e;
    }
#pragma unroll
    for (int off = 1; off < 64; off <<= 1) sum += __shfl_xor(sum, off);
    if (lane == 0) invd[w] = 1.f / sum;
  }
  __syncthreads();

  // normalized attn write (in-place over raw scores)
#pragma unroll
  for (int r = 0; r < 8; ++r) {
    const int idx = tid + r * 512;
    const int h = idx >> 9, m = idx & 511;
    attn[(size_t)h * 262144 + n * 512 + m] = sc[idx] * invd[h];
  }

  // hidden[n,c] = (sum_m p[h][m] * v[m,c]) * invd[h]; split m across 2 thread-halves
  const int c = tid & 255, half = tid >> 8, h2 = c >> 5;
  const float* pr = sc + h2 * 512 + half * 256;
  const float* vp = v_g + (size_t)half * 65536 + c;
  float acc = 0.f;
#pragma unroll 4
  for (int m4 = 0; m4 < 64; ++m4) {
    const float4 p4 = *(const float4*)(pr + m4 * 4);
    const int mb = m4 * 4;
    acc = fmaf(p4.x, vp[(size_t)(mb + 0) * 256], acc);
    acc = fmaf(p4.y, vp[(size_t)(mb + 1) * 256], acc);
    acc = fmaf(p4.z, vp[(size_t)(mb + 2) * 256], acc);
    acc = fmaf(p4.w, vp[(size_t)(mb + 3) * 256], acc);
  }
  pv[half][c] = acc;
  __syncthreads();
  if (tid < 256) out[n * 256 + tid] = (pv[0][tid] + pv[1][tid]) * invd[tid >> 5];
}

extern "C" void kernel_launch(void* const* d_in, const int* in_sizes, int n_in,
                              void* d_out, int out_size, void* d_ws, size_t ws_size,
                              hipStream_t stream) {
  const float* query = (const float*)d_in[0];
  const float* key   = (const float*)d_in[1];
  const float* value = (const float*)d_in[2];
  const float* Eg    = (const float*)d_in[3];
  const float* Wq    = (const float*)d_in[4];
  const float* bq    = (const float*)d_in[5];
  const float* Wk    = (const float*)d_in[6];
  const float* bk    = (const float*)d_in[7];
  const float* Wv    = (const float*)d_in[8];
  const float* bv    = (const float*)d_in[9];
  const float* Wg    = (const float*)d_in[10];
  const float* bg    = (const float*)d_in[11];
  float* out = (float*)d_out;

  // ws layout (floats): wt[3*65536] | qkv[3*131072] | t_ws[512*2048] | qb_ws[4096]  ≈ 6.6 MB
  float* ws = (float*)d_ws;
  float* wt = ws;
  float* qkv = wt + 3 * 65536;
  float* t_ws = qkv + 3 * 131072;
  float* qb_ws = t_ws + 512 * 2048;

  k_transpose<<<dim3(16, 3), 256, 0, stream>>>(Wq, Wk, Wv, wt);
  k_proj<<<dim3(64, 3), 256, 0, stream>>>(query, key, value, bq, bk, bv, wt, qkv);
  k_tfold<<<dim3(8, 8), 256, 0, stream>>>(qkv, Wg, bg, t_ws, qb_ws);
  k_scores<<<dim3(512, 4), 256, 0, stream>>>(Eg, qkv, t_ws, qb_ws, out + 131072);
  k_finish<<<dim3(512), 512, 0, stream>>>(qkv, out);
}